// Round 1
// baseline (1268.056 us; speedup 1.0000x reference)
//
#include <hip/hip_runtime.h>
#include <hip/hip_bf16.h>

// Problem constants (HeteroGATLayer): H=4 heads, D=16, IN=64, E=400000, N=100000
constexpr int IN_F = 64;   // input feature dim
constexpr int HD   = 64;   // H*D
constexpr int BN   = 64;   // nodes per projection block

// ---------------------------------------------------------------------------
// Projection kernel: for each node type t (blockIdx.y), compute
//   proj 0: h_self = feat@W_t + b_t  -> ddot_r[n,h] for the 3 rels with dst==t
//   proj 1..3: Wh_r = feat@W_r + b_r -> store bf16 Wh_r row + sdot_r[n,h]
// rel index ri = src*3 + dst  (RELS order c1c1,c1c2,c1c3,c2c1,...)
// ---------------------------------------------------------------------------
struct ProjParams {
  const float* feat[3];
  const float* Wp[3][4];     // [type][proj]; proj0=self, proj p>=1 -> rel t*3+(p-1)
  const float* bp[3][4];
  const float* adst[9];      // [H*D]
  const float* asrc[9];
  __hip_bfloat16* wh[9];     // out: [N, 64] bf16
  float* sdot[9];            // out: [N, 4]
  float* ddot[9];            // out: [N, 4]
  int N;
};

__global__ __launch_bounds__(256) void proj_kernel(ProjParams p) {
  const int t  = blockIdx.y;
  const int n0 = blockIdx.x * BN;
  const int tid = threadIdx.x;
  const int N = p.N;

  __shared__ float featL[BN][IN_F + 1];   // +1 pad: conflict-free column reads
  __shared__ float WL[IN_F][HD];

  // stage feature tile (64 rows x 64 cols), float4 loads
  {
    const float* feat = p.feat[t];
    for (int i = tid; i < BN * (IN_F / 4); i += 256) {
      const int row = i >> 4;
      const int c4  = (i & 15) << 2;
      float4 v = make_float4(0.f, 0.f, 0.f, 0.f);
      const int n = n0 + row;
      if (n < N) v = *(const float4*)(feat + (size_t)n * IN_F + c4);
      featL[row][c4 + 0] = v.x; featL[row][c4 + 1] = v.y;
      featL[row][c4 + 2] = v.z; featL[row][c4 + 3] = v.w;
    }
  }

  const int node = tid >> 2;      // 0..63
  const int cg   = tid & 3;       // head index (D==16 so col-group == head)
  const int cg16 = cg * 16;
  const int n    = n0 + node;

  for (int pr = 0; pr < 4; ++pr) {
    __syncthreads();
    // stage W (64x64)
    {
      const float* W = p.Wp[t][pr];
      for (int i = tid; i < IN_F * HD / 4; i += 256) {
        *(float4*)(&WL[0][0] + i * 4) = *(const float4*)(W + i * 4);
      }
    }
    __syncthreads();

    const float* b = p.bp[t][pr];
    float acc[16];
    #pragma unroll
    for (int jj = 0; jj < 16; ++jj) acc[jj] = b[cg16 + jj];

    #pragma unroll 4
    for (int k = 0; k < IN_F; ++k) {
      const float a = featL[node][k];
      const float4 w0 = *(const float4*)(&WL[k][cg16 + 0]);
      const float4 w1 = *(const float4*)(&WL[k][cg16 + 4]);
      const float4 w2 = *(const float4*)(&WL[k][cg16 + 8]);
      const float4 w3 = *(const float4*)(&WL[k][cg16 + 12]);
      acc[0]  = fmaf(a, w0.x, acc[0]);  acc[1]  = fmaf(a, w0.y, acc[1]);
      acc[2]  = fmaf(a, w0.z, acc[2]);  acc[3]  = fmaf(a, w0.w, acc[3]);
      acc[4]  = fmaf(a, w1.x, acc[4]);  acc[5]  = fmaf(a, w1.y, acc[5]);
      acc[6]  = fmaf(a, w1.z, acc[6]);  acc[7]  = fmaf(a, w1.w, acc[7]);
      acc[8]  = fmaf(a, w2.x, acc[8]);  acc[9]  = fmaf(a, w2.y, acc[9]);
      acc[10] = fmaf(a, w2.z, acc[10]); acc[11] = fmaf(a, w2.w, acc[11]);
      acc[12] = fmaf(a, w3.x, acc[12]); acc[13] = fmaf(a, w3.y, acc[13]);
      acc[14] = fmaf(a, w3.z, acc[14]); acc[15] = fmaf(a, w3.w, acc[15]);
    }

    if (n < N) {
      if (pr == 0) {
        // self projection -> ddot for the 3 relations whose dst type is t
        #pragma unroll
        for (int sj = 0; sj < 3; ++sj) {
          const int ri = sj * 3 + t;
          const float* ad = p.adst[ri] + cg16;
          float s = 0.f;
          #pragma unroll
          for (int jj = 0; jj < 16; ++jj) s = fmaf(acc[jj], ad[jj], s);
          p.ddot[ri][(size_t)n * 4 + cg] = s;
        }
      } else {
        const int ri = t * 3 + (pr - 1);
        __hip_bfloat16* whp = p.wh[ri] + (size_t)n * HD + cg16;
        #pragma unroll
        for (int jj = 0; jj < 16; ++jj) whp[jj] = __float2bfloat16(acc[jj]);
        const float* as = p.asrc[ri] + cg16;
        float s = 0.f;
        #pragma unroll
        for (int jj = 0; jj < 16; ++jj) s = fmaf(acc[jj], as[jj], s);
        p.sdot[ri][(size_t)n * 4 + cg] = s;
      }
    }
  }
}

// ---------------------------------------------------------------------------
// Edge kernel: one 64-lane wave per edge. blockIdx.y = relation.
// logits e_h = lrelu(sdot[src,h] + ddot[dst,h]); alpha = softmax over 4 heads;
// out[dst] += alpha[h] * Wh_r[src]   (atomicAdd per element)
// ---------------------------------------------------------------------------
struct EdgeParams {
  const int* src[9];
  const int* dst[9];
  const float* sdot[9];
  const float* ddot[9];
  const __hip_bfloat16* wh[9];
  float* outp[3];
  int E;
};

__global__ __launch_bounds__(256) void edge_kernel(EdgeParams p) {
  const int r = blockIdx.y;
  const int e = blockIdx.x * 4 + (threadIdx.x >> 6);
  if (e >= p.E) return;
  const int lane = threadIdx.x & 63;

  const int s  = p.src[r][e];
  const int dn = p.dst[r][e];

  const float4 sd = *(const float4*)(p.sdot[r] + (size_t)s * 4);
  const float4 dd = *(const float4*)(p.ddot[r] + (size_t)dn * 4);

  float e0 = sd.x + dd.x, e1 = sd.y + dd.y, e2 = sd.z + dd.z, e3 = sd.w + dd.w;
  e0 = (e0 >= 0.f) ? e0 : 0.2f * e0;
  e1 = (e1 >= 0.f) ? e1 : 0.2f * e1;
  e2 = (e2 >= 0.f) ? e2 : 0.2f * e2;
  e3 = (e3 >= 0.f) ? e3 : 0.2f * e3;
  const float m = fmaxf(fmaxf(e0, e1), fmaxf(e2, e3));
  const float x0 = __expf(e0 - m);
  const float x1 = __expf(e1 - m);
  const float x2 = __expf(e2 - m);
  const float x3 = __expf(e3 - m);
  const float inv = 1.f / (x0 + x1 + x2 + x3);

  const float wh = __bfloat162float(p.wh[r][(size_t)s * HD + lane]);
  const int h = lane >> 4;
  const float a = ((h == 0) ? x0 : (h == 1) ? x1 : (h == 2) ? x2 : x3) * inv;

  atomicAdd(p.outp[r % 3] + (size_t)dn * HD + lane, wh * a);
}

// ---------------------------------------------------------------------------
__global__ __launch_bounds__(256) void zero_kernel(float4* out, int n4) {
  const int i = blockIdx.x * 256 + threadIdx.x;
  if (i < n4) out[i] = make_float4(0.f, 0.f, 0.f, 0.f);
}

__global__ __launch_bounds__(256) void relu_kernel(float4* out, int n4) {
  const int i = blockIdx.x * 256 + threadIdx.x;
  if (i < n4) {
    float4 v = out[i];
    v.x = fmaxf(v.x, 0.f); v.y = fmaxf(v.y, 0.f);
    v.z = fmaxf(v.z, 0.f); v.w = fmaxf(v.w, 0.f);
    out[i] = v;
  }
}

// ---------------------------------------------------------------------------
// d_in layout (setup_inputs dict order):
//   t in {0,1,2}: [t*3+0]=feat_t, [t*3+1]=W_t, [t*3+2]=b_t
//   rel ri in {0..8}: base=9+ri*6: W, b, asrc, adst, src, dst
// d_out: concat(relu(agg_C1), relu(agg_C2), relu(agg_C3)), each N*64 f32
// ---------------------------------------------------------------------------
extern "C" void kernel_launch(void* const* d_in, const int* in_sizes, int n_in,
                              void* d_out, int out_size, void* d_ws, size_t ws_size,
                              hipStream_t stream) {
  const int N = in_sizes[0] / IN_F;     // 100000
  const int E = in_sizes[9 + 4];        // src_c1c1 length = 400000

  ProjParams pp;
  EdgeParams ep;
  pp.N = N;
  ep.E = E;

  for (int t = 0; t < 3; ++t) {
    pp.feat[t]  = (const float*)d_in[t * 3 + 0];
    pp.Wp[t][0] = (const float*)d_in[t * 3 + 1];
    pp.bp[t][0] = (const float*)d_in[t * 3 + 2];
    for (int j = 0; j < 3; ++j) {
      const int base = 9 + (t * 3 + j) * 6;
      pp.Wp[t][1 + j] = (const float*)d_in[base + 0];
      pp.bp[t][1 + j] = (const float*)d_in[base + 1];
    }
  }

  char* ws = (char*)d_ws;
  const size_t whBytes  = (size_t)N * HD * sizeof(__hip_bfloat16); // 12.8 MB
  const size_t dotBytes = (size_t)N * 4 * sizeof(float);           // 1.6 MB
  for (int ri = 0; ri < 9; ++ri) {
    const int base = 9 + ri * 6;
    pp.asrc[ri] = (const float*)d_in[base + 2];
    pp.adst[ri] = (const float*)d_in[base + 3];
    pp.wh[ri]   = (__hip_bfloat16*)(ws + (size_t)ri * whBytes);
    pp.sdot[ri] = (float*)(ws + 9 * whBytes + (size_t)ri * dotBytes);
    pp.ddot[ri] = (float*)(ws + 9 * whBytes + 9 * dotBytes + (size_t)ri * dotBytes);
    ep.src[ri]  = (const int*)d_in[base + 4];
    ep.dst[ri]  = (const int*)d_in[base + 5];
    ep.wh[ri]   = pp.wh[ri];
    ep.sdot[ri] = pp.sdot[ri];
    ep.ddot[ri] = pp.ddot[ri];
  }
  for (int t = 0; t < 3; ++t) ep.outp[t] = (float*)d_out + (size_t)t * N * HD;

  const int n4 = out_size / 4;  // 4.8M float4s

  zero_kernel<<<dim3((n4 + 255) / 256), 256, 0, stream>>>((float4*)d_out, n4);
  proj_kernel<<<dim3((N + BN - 1) / BN, 3), 256, 0, stream>>>(pp);
  edge_kernel<<<dim3((E + 3) / 4, 9), 256, 0, stream>>>(ep);
  relu_kernel<<<dim3((n4 + 255) / 256), 256, 0, stream>>>((float4*)d_out, n4);
}

// Round 2
// 1179.985 us; speedup vs baseline: 1.0746x; 1.0746x over previous
//
#include <hip/hip_runtime.h>
#include <hip/hip_bf16.h>

// Problem constants (HeteroGATLayer): H=4 heads, D=16, IN=64, E=400000, N=100000
constexpr int IN_F = 64;   // input feature dim
constexpr int HD   = 64;   // H*D
constexpr int BN   = 64;   // nodes per projection block

// ---------------------------------------------------------------------------
// Projection kernel (unchanged from R1): for each node type t (blockIdx.y):
//   proj 0: h_self = feat@W_t + b_t  -> ddot_r[n,h] for the 3 rels with dst==t
//   proj 1..3: Wh_r = feat@W_r + b_r -> store bf16 Wh_r row + sdot_r[n,h]
// ---------------------------------------------------------------------------
struct ProjParams {
  const float* feat[3];
  const float* Wp[3][4];
  const float* bp[3][4];
  const float* adst[9];
  const float* asrc[9];
  __hip_bfloat16* wh[9];     // out: [N, 64] bf16
  float* sdot[9];            // out: [N, 4]
  float* ddot[9];            // out: [N, 4]
  int N;
};

__global__ __launch_bounds__(256) void proj_kernel(ProjParams p) {
  const int t  = blockIdx.y;
  const int n0 = blockIdx.x * BN;
  const int tid = threadIdx.x;
  const int N = p.N;

  __shared__ float featL[BN][IN_F + 1];
  __shared__ float WL[IN_F][HD];

  {
    const float* feat = p.feat[t];
    for (int i = tid; i < BN * (IN_F / 4); i += 256) {
      const int row = i >> 4;
      const int c4  = (i & 15) << 2;
      float4 v = make_float4(0.f, 0.f, 0.f, 0.f);
      const int n = n0 + row;
      if (n < N) v = *(const float4*)(feat + (size_t)n * IN_F + c4);
      featL[row][c4 + 0] = v.x; featL[row][c4 + 1] = v.y;
      featL[row][c4 + 2] = v.z; featL[row][c4 + 3] = v.w;
    }
  }

  const int node = tid >> 2;
  const int cg   = tid & 3;       // head index
  const int cg16 = cg * 16;
  const int n    = n0 + node;

  for (int pr = 0; pr < 4; ++pr) {
    __syncthreads();
    {
      const float* W = p.Wp[t][pr];
      for (int i = tid; i < IN_F * HD / 4; i += 256) {
        *(float4*)(&WL[0][0] + i * 4) = *(const float4*)(W + i * 4);
      }
    }
    __syncthreads();

    const float* b = p.bp[t][pr];
    float acc[16];
    #pragma unroll
    for (int jj = 0; jj < 16; ++jj) acc[jj] = b[cg16 + jj];

    #pragma unroll 4
    for (int k = 0; k < IN_F; ++k) {
      const float a = featL[node][k];
      const float4 w0 = *(const float4*)(&WL[k][cg16 + 0]);
      const float4 w1 = *(const float4*)(&WL[k][cg16 + 4]);
      const float4 w2 = *(const float4*)(&WL[k][cg16 + 8]);
      const float4 w3 = *(const float4*)(&WL[k][cg16 + 12]);
      acc[0]  = fmaf(a, w0.x, acc[0]);  acc[1]  = fmaf(a, w0.y, acc[1]);
      acc[2]  = fmaf(a, w0.z, acc[2]);  acc[3]  = fmaf(a, w0.w, acc[3]);
      acc[4]  = fmaf(a, w1.x, acc[4]);  acc[5]  = fmaf(a, w1.y, acc[5]);
      acc[6]  = fmaf(a, w1.z, acc[6]);  acc[7]  = fmaf(a, w1.w, acc[7]);
      acc[8]  = fmaf(a, w2.x, acc[8]);  acc[9]  = fmaf(a, w2.y, acc[9]);
      acc[10] = fmaf(a, w2.z, acc[10]); acc[11] = fmaf(a, w2.w, acc[11]);
      acc[12] = fmaf(a, w3.x, acc[12]); acc[13] = fmaf(a, w3.y, acc[13]);
      acc[14] = fmaf(a, w3.z, acc[14]); acc[15] = fmaf(a, w3.w, acc[15]);
    }

    if (n < N) {
      if (pr == 0) {
        #pragma unroll
        for (int sj = 0; sj < 3; ++sj) {
          const int ri = sj * 3 + t;
          const float* ad = p.adst[ri] + cg16;
          float s = 0.f;
          #pragma unroll
          for (int jj = 0; jj < 16; ++jj) s = fmaf(acc[jj], ad[jj], s);
          p.ddot[ri][(size_t)n * 4 + cg] = s;
        }
      } else {
        const int ri = t * 3 + (pr - 1);
        __hip_bfloat16* whp = p.wh[ri] + (size_t)n * HD + cg16;
        #pragma unroll
        for (int jj = 0; jj < 16; ++jj) whp[jj] = __float2bfloat16(acc[jj]);
        const float* as = p.asrc[ri] + cg16;
        float s = 0.f;
        #pragma unroll
        for (int jj = 0; jj < 16; ++jj) s = fmaf(acc[jj], as[jj], s);
        p.sdot[ri][(size_t)n * 4 + cg] = s;
      }
    }
  }
}

// ---------------------------------------------------------------------------
// CSR build: histogram -> scan -> scatter (src ids in dst-sorted order)
// ---------------------------------------------------------------------------
constexpr int SCAN_TPB   = 256;
constexpr int SCAN_ELEMS = 8;
constexpr int SCAN_CHUNK = SCAN_TPB * SCAN_ELEMS;  // 2048

__global__ __launch_bounds__(256) void zero_u32_kernel(unsigned* p, int n) {
  const int i = blockIdx.x * 256 + threadIdx.x;
  if (i < n) p[i] = 0u;
}

struct EdgeLists { const int* src[9]; const int* dst[9]; int E; int N; };

__global__ __launch_bounds__(256) void hist_kernel(EdgeLists el, unsigned* counts) {
  const int r = blockIdx.y;
  const int e = blockIdx.x * 256 + threadIdx.x;
  if (e < el.E) atomicAdd(counts + (size_t)r * el.N + el.dst[r][e], 1u);
}

// per-block sums of 2048-element chunks
__global__ __launch_bounds__(SCAN_TPB) void scan1_kernel(const unsigned* counts,
                                                         unsigned* partials,
                                                         int N, int nblk) {
  const int r = blockIdx.y;
  const int b = blockIdx.x;
  const unsigned* c = counts + (size_t)r * N;
  const int base = b * SCAN_CHUNK + threadIdx.x * SCAN_ELEMS;
  unsigned s = 0;
  #pragma unroll
  for (int i = 0; i < SCAN_ELEMS; ++i) {
    const int idx = base + i;
    if (idx < N) s += c[idx];
  }
  __shared__ unsigned red[SCAN_TPB];
  red[threadIdx.x] = s;
  __syncthreads();
  for (int off = SCAN_TPB / 2; off > 0; off >>= 1) {
    if (threadIdx.x < off) red[threadIdx.x] += red[threadIdx.x + off];
    __syncthreads();
  }
  if (threadIdx.x == 0) partials[(size_t)r * nblk + b] = red[0];
}

// exclusive scan of the (small) per-block partials, one block per relation
__global__ __launch_bounds__(64) void scan2_kernel(unsigned* partials, int nblk) {
  const int r = blockIdx.x;
  unsigned* p = partials + (size_t)r * nblk;
  if (threadIdx.x == 0) {
    unsigned run = 0;
    for (int i = 0; i < nblk; ++i) { const unsigned v = p[i]; p[i] = run; run += v; }
  }
}

// local exclusive scan + global offset -> offsets[] and cursor[]
__global__ __launch_bounds__(SCAN_TPB) void scan3_kernel(const unsigned* counts,
                                                         const unsigned* partials,
                                                         unsigned* offsets,
                                                         unsigned* cursor,
                                                         int N, int nblk, int E) {
  const int r = blockIdx.y;
  const int b = blockIdx.x;
  const unsigned* c = counts + (size_t)r * N;
  unsigned* off = offsets + (size_t)r * (N + 1);
  unsigned* cur = cursor + (size_t)r * N;
  const int base = b * SCAN_CHUNK + threadIdx.x * SCAN_ELEMS;
  unsigned loc[SCAN_ELEMS];
  unsigned s = 0;
  #pragma unroll
  for (int i = 0; i < SCAN_ELEMS; ++i) {
    const int idx = base + i;
    const unsigned v = (idx < N) ? c[idx] : 0u;
    loc[i] = v; s += v;
  }
  __shared__ unsigned tsum[SCAN_TPB];
  tsum[threadIdx.x] = s;
  __syncthreads();
  for (int d = 1; d < SCAN_TPB; d <<= 1) {
    const unsigned v = tsum[threadIdx.x];
    const unsigned a = (threadIdx.x >= d) ? tsum[threadIdx.x - d] : 0u;
    __syncthreads();
    tsum[threadIdx.x] = v + a;
    __syncthreads();
  }
  unsigned run = partials[(size_t)r * nblk + b] + tsum[threadIdx.x] - s;  // exclusive
  #pragma unroll
  for (int i = 0; i < SCAN_ELEMS; ++i) {
    const int idx = base + i;
    if (idx < N) { off[idx] = run; cur[idx] = run; run += loc[i]; }
  }
  if (b == 0 && threadIdx.x == 0) off[N] = (unsigned)E;
}

__global__ __launch_bounds__(256) void scatter_kernel(EdgeLists el, unsigned* cursor,
                                                      unsigned* perm) {
  const int r = blockIdx.y;
  const int e = blockIdx.x * 256 + threadIdx.x;
  if (e < el.E) {
    const int d = el.dst[r][e];
    const unsigned pos = atomicAdd(cursor + (size_t)r * el.N + d, 1u);
    perm[(size_t)r * el.E + pos] = (unsigned)el.src[r][e];  // store src directly
  }
}

// ---------------------------------------------------------------------------
// Aggregation: one 64-lane wave per (dst node, type). No output atomics.
//   acc[lane] = sum over incoming edges of alpha[h]*wh[src][lane]; relu; store.
// ---------------------------------------------------------------------------
struct AggParams {
  const unsigned* offsets[9];   // [N+1] each
  const unsigned* perm[9];      // [E] src ids in dst order
  const float* sdot[9];
  const float* ddot[9];
  const __hip_bfloat16* wh[9];
  float* outp[3];
  int N, E;
};

__global__ __launch_bounds__(256) void agg_kernel(AggParams p) {
  const int t    = blockIdx.y;
  const int w    = threadIdx.x >> 6;
  const int lane = threadIdx.x & 63;
  const int n    = blockIdx.x * 4 + w;
  if (n >= p.N) return;
  const int h = lane >> 4;

  float acc = 0.f;
  #pragma unroll
  for (int sj = 0; sj < 3; ++sj) {
    const int r = sj * 3 + t;
    const unsigned start = p.offsets[r][n];
    const unsigned end   = p.offsets[r][n + 1];
    if (start == end) continue;
    const float4 dd = *(const float4*)(p.ddot[r] + (size_t)n * 4);  // wave-uniform
    const __hip_bfloat16* whr = p.wh[r];
    const float* sdr = p.sdot[r];
    const unsigned* pm = p.perm[r];

    for (unsigned base = start; base < end; base += 64) {
      const int cnt = (int)min(64u, end - base);
      int sv = 0;
      float4 a4 = make_float4(0.f, 0.f, 0.f, 0.f);
      if (lane < cnt) {
        sv = (int)pm[base + lane];
        const float4 sd = *(const float4*)(sdr + (size_t)sv * 4);
        float e0 = sd.x + dd.x, e1 = sd.y + dd.y, e2 = sd.z + dd.z, e3 = sd.w + dd.w;
        e0 = (e0 >= 0.f) ? e0 : 0.2f * e0;
        e1 = (e1 >= 0.f) ? e1 : 0.2f * e1;
        e2 = (e2 >= 0.f) ? e2 : 0.2f * e2;
        e3 = (e3 >= 0.f) ? e3 : 0.2f * e3;
        const float m = fmaxf(fmaxf(e0, e1), fmaxf(e2, e3));
        const float x0 = __expf(e0 - m);
        const float x1 = __expf(e1 - m);
        const float x2 = __expf(e2 - m);
        const float x3 = __expf(e3 - m);
        const float inv = 1.f / (x0 + x1 + x2 + x3);
        a4 = make_float4(x0 * inv, x1 * inv, x2 * inv, x3 * inv);
      }
      for (int j = 0; j < cnt; ++j) {
        const int s   = __shfl(sv, j);
        const float b0 = __shfl(a4.x, j);
        const float b1 = __shfl(a4.y, j);
        const float b2 = __shfl(a4.z, j);
        const float b3 = __shfl(a4.w, j);
        const float a = (h == 0) ? b0 : (h == 1) ? b1 : (h == 2) ? b2 : b3;
        const float whv = __bfloat162float(whr[(size_t)s * HD + lane]);
        acc = fmaf(a, whv, acc);
      }
    }
  }
  p.outp[t][(size_t)n * HD + lane] = fmaxf(acc, 0.f);
}

// ---------------------------------------------------------------------------
extern "C" void kernel_launch(void* const* d_in, const int* in_sizes, int n_in,
                              void* d_out, int out_size, void* d_ws, size_t ws_size,
                              hipStream_t stream) {
  const int N = in_sizes[0] / IN_F;     // 100000
  const int E = in_sizes[9 + 4];        // 400000

  ProjParams pp; AggParams ap; EdgeLists el;
  pp.N = N; ap.N = N; ap.E = E; el.E = E; el.N = N;

  for (int t = 0; t < 3; ++t) {
    pp.feat[t]  = (const float*)d_in[t * 3 + 0];
    pp.Wp[t][0] = (const float*)d_in[t * 3 + 1];
    pp.bp[t][0] = (const float*)d_in[t * 3 + 2];
    for (int j = 0; j < 3; ++j) {
      const int base = 9 + (t * 3 + j) * 6;
      pp.Wp[t][1 + j] = (const float*)d_in[base + 0];
      pp.bp[t][1 + j] = (const float*)d_in[base + 1];
    }
  }

  // workspace carve-up
  char* ws = (char*)d_ws;
  const size_t whBytes  = (size_t)N * HD * sizeof(__hip_bfloat16); // 12.8 MB
  const size_t dotBytes = (size_t)N * 4 * sizeof(float);           // 1.6 MB
  char* whBase   = ws;                              // 9 * 12.8 MB
  char* sdotBase = whBase + 9 * whBytes;            // 9 * 1.6 MB
  char* ddotBase = sdotBase + 9 * dotBytes;         // 9 * 1.6 MB
  unsigned* counts  = (unsigned*)(ddotBase + 9 * dotBytes);        // 9*N u32
  unsigned* cursor  = counts + (size_t)9 * N;                      // 9*N u32
  unsigned* offsets = cursor + (size_t)9 * N;                      // 9*(N+1) u32
  unsigned* partials = offsets + (size_t)9 * (N + 1);              // 9*nblk u32
  const int nblk = (N + SCAN_CHUNK - 1) / SCAN_CHUNK;              // 49
  unsigned* perm = partials + (size_t)9 * ((nblk + 63) & ~63);     // 9*E u32

  for (int ri = 0; ri < 9; ++ri) {
    const int base = 9 + ri * 6;
    pp.asrc[ri] = (const float*)d_in[base + 2];
    pp.adst[ri] = (const float*)d_in[base + 3];
    pp.wh[ri]   = (__hip_bfloat16*)(whBase + (size_t)ri * whBytes);
    pp.sdot[ri] = (float*)(sdotBase + (size_t)ri * dotBytes);
    pp.ddot[ri] = (float*)(ddotBase + (size_t)ri * dotBytes);
    el.src[ri]  = (const int*)d_in[base + 4];
    el.dst[ri]  = (const int*)d_in[base + 5];
    ap.wh[ri]   = pp.wh[ri];
    ap.sdot[ri] = pp.sdot[ri];
    ap.ddot[ri] = pp.ddot[ri];
    ap.offsets[ri] = offsets + (size_t)ri * (N + 1);
    ap.perm[ri]    = perm + (size_t)ri * E;
  }
  for (int t = 0; t < 3; ++t) ap.outp[t] = (float*)d_out + (size_t)t * N * HD;

  // ---- CSR build ----
  const int nCounts = 9 * N;
  zero_u32_kernel<<<dim3((nCounts + 255) / 256), 256, 0, stream>>>(counts, nCounts);
  hist_kernel<<<dim3((E + 255) / 256, 9), 256, 0, stream>>>(el, counts);
  scan1_kernel<<<dim3(nblk, 9), SCAN_TPB, 0, stream>>>(counts, partials, N, nblk);
  scan2_kernel<<<dim3(9), 64, 0, stream>>>(partials, nblk);
  scan3_kernel<<<dim3(nblk, 9), SCAN_TPB, 0, stream>>>(counts, partials, offsets, cursor, N, nblk, E);
  scatter_kernel<<<dim3((E + 255) / 256, 9), 256, 0, stream>>>(el, cursor, perm);

  // ---- projections ----
  proj_kernel<<<dim3((N + BN - 1) / BN, 3), 256, 0, stream>>>(pp);

  // ---- dst-centric aggregation (writes every output element, fused relu) ----
  agg_kernel<<<dim3(N / 4, 3), 256, 0, stream>>>(ap);
}

// Round 3
// 995.839 us; speedup vs baseline: 1.2734x; 1.1849x over previous
//
#include <hip/hip_runtime.h>
#include <hip/hip_bf16.h>

// Problem constants (HeteroGATLayer): H=4 heads, D=16, IN=64, E=400000, N=100000
constexpr int IN_F = 64;   // input feature dim
constexpr int HD   = 64;   // H*D
constexpr int BN   = 128;  // nodes per projection block (2 per thread)

static __device__ __forceinline__ float bf2f(unsigned short u) {
  union { unsigned int i; float f; } c; c.i = ((unsigned int)u) << 16; return c.f;
}
static __device__ __forceinline__ unsigned short f2bf_bits(float f) {
  union { __hip_bfloat16 h; unsigned short u; } c; c.h = __float2bfloat16(f); return c.u;
}

// ---------------------------------------------------------------------------
// Projection kernel: for each node type t (blockIdx.y), 2 nodes per thread:
//   proj 0: h_self = feat@W_t + b_t  -> ddot_r[n,h] for the 3 rels with dst==t
//   proj 1..3: Wh_r = feat@W_r + b_r -> store bf16 Wh_r row + sdot_r[n,h]
// ---------------------------------------------------------------------------
struct ProjParams {
  const float* feat[3];
  const float* Wp[3][4];
  const float* bp[3][4];
  const float* adst[9];
  const float* asrc[9];
  __hip_bfloat16* wh[9];     // out: [N, 64] bf16
  float* sdot[9];            // out: [N, 4]
  float* ddot[9];            // out: [N, 4]
  int N;
};

__global__ __launch_bounds__(256) void proj_kernel(ProjParams p) {
  const int t  = blockIdx.y;
  const int n0 = blockIdx.x * BN;
  const int tid = threadIdx.x;
  const int N = p.N;

  __shared__ float featL[BN][IN_F + 1];   // 33.3 KB
  __shared__ float WL[IN_F][HD];          // 16 KB

  {
    const float* feat = p.feat[t];
    for (int i = tid; i < BN * (IN_F / 4); i += 256) {
      const int row = i >> 4;
      const int c4  = (i & 15) << 2;
      float4 v = make_float4(0.f, 0.f, 0.f, 0.f);
      const int n = n0 + row;
      if (n < N) v = *(const float4*)(feat + (size_t)n * IN_F + c4);
      featL[row][c4 + 0] = v.x; featL[row][c4 + 1] = v.y;
      featL[row][c4 + 2] = v.z; featL[row][c4 + 3] = v.w;
    }
  }

  const int node = tid >> 2;      // 0..63
  const int cg   = tid & 3;       // head index (16 cols per head)
  const int cg16 = cg * 16;
  const int nA   = n0 + node;
  const int nB   = n0 + node + 64;

  for (int pr = 0; pr < 4; ++pr) {
    __syncthreads();
    {
      const float* W = p.Wp[t][pr];
      for (int i = tid; i < IN_F * HD / 4; i += 256) {
        *(float4*)(&WL[0][0] + i * 4) = *(const float4*)(W + i * 4);
      }
    }
    __syncthreads();

    const float* b = p.bp[t][pr];
    float acc0[16], acc1[16];
    #pragma unroll
    for (int jj = 0; jj < 16; ++jj) { acc0[jj] = b[cg16 + jj]; acc1[jj] = acc0[jj]; }

    #pragma unroll 4
    for (int k = 0; k < IN_F; ++k) {
      const float a0 = featL[node][k];
      const float a1 = featL[node + 64][k];
      const float4 w0 = *(const float4*)(&WL[k][cg16 + 0]);
      const float4 w1 = *(const float4*)(&WL[k][cg16 + 4]);
      const float4 w2 = *(const float4*)(&WL[k][cg16 + 8]);
      const float4 w3 = *(const float4*)(&WL[k][cg16 + 12]);
      acc0[0]  = fmaf(a0, w0.x, acc0[0]);  acc0[1]  = fmaf(a0, w0.y, acc0[1]);
      acc0[2]  = fmaf(a0, w0.z, acc0[2]);  acc0[3]  = fmaf(a0, w0.w, acc0[3]);
      acc0[4]  = fmaf(a0, w1.x, acc0[4]);  acc0[5]  = fmaf(a0, w1.y, acc0[5]);
      acc0[6]  = fmaf(a0, w1.z, acc0[6]);  acc0[7]  = fmaf(a0, w1.w, acc0[7]);
      acc0[8]  = fmaf(a0, w2.x, acc0[8]);  acc0[9]  = fmaf(a0, w2.y, acc0[9]);
      acc0[10] = fmaf(a0, w2.z, acc0[10]); acc0[11] = fmaf(a0, w2.w, acc0[11]);
      acc0[12] = fmaf(a0, w3.x, acc0[12]); acc0[13] = fmaf(a0, w3.y, acc0[13]);
      acc0[14] = fmaf(a0, w3.z, acc0[14]); acc0[15] = fmaf(a0, w3.w, acc0[15]);
      acc1[0]  = fmaf(a1, w0.x, acc1[0]);  acc1[1]  = fmaf(a1, w0.y, acc1[1]);
      acc1[2]  = fmaf(a1, w0.z, acc1[2]);  acc1[3]  = fmaf(a1, w0.w, acc1[3]);
      acc1[4]  = fmaf(a1, w1.x, acc1[4]);  acc1[5]  = fmaf(a1, w1.y, acc1[5]);
      acc1[6]  = fmaf(a1, w1.z, acc1[6]);  acc1[7]  = fmaf(a1, w1.w, acc1[7]);
      acc1[8]  = fmaf(a1, w2.x, acc1[8]);  acc1[9]  = fmaf(a1, w2.y, acc1[9]);
      acc1[10] = fmaf(a1, w2.z, acc1[10]); acc1[11] = fmaf(a1, w2.w, acc1[11]);
      acc1[12] = fmaf(a1, w3.x, acc1[12]); acc1[13] = fmaf(a1, w3.y, acc1[13]);
      acc1[14] = fmaf(a1, w3.z, acc1[14]); acc1[15] = fmaf(a1, w3.w, acc1[15]);
    }

    if (pr == 0) {
      #pragma unroll
      for (int sj = 0; sj < 3; ++sj) {
        const int ri = sj * 3 + t;
        const float* ad = p.adst[ri] + cg16;
        float s0 = 0.f, s1 = 0.f;
        #pragma unroll
        for (int jj = 0; jj < 16; ++jj) {
          const float av = ad[jj];
          s0 = fmaf(acc0[jj], av, s0);
          s1 = fmaf(acc1[jj], av, s1);
        }
        if (nA < N) p.ddot[ri][(size_t)nA * 4 + cg] = s0;
        if (nB < N) p.ddot[ri][(size_t)nB * 4 + cg] = s1;
      }
    } else {
      const int ri = t * 3 + (pr - 1);
      const float* as = p.asrc[ri] + cg16;
      float s0 = 0.f, s1 = 0.f;
      #pragma unroll
      for (int jj = 0; jj < 16; ++jj) {
        const float av = as[jj];
        s0 = fmaf(acc0[jj], av, s0);
        s1 = fmaf(acc1[jj], av, s1);
      }
      if (nA < N) {
        __hip_bfloat16* whp = p.wh[ri] + (size_t)nA * HD + cg16;
        #pragma unroll
        for (int jj = 0; jj < 16; ++jj) whp[jj] = __float2bfloat16(acc0[jj]);
        p.sdot[ri][(size_t)nA * 4 + cg] = s0;
      }
      if (nB < N) {
        __hip_bfloat16* whp = p.wh[ri] + (size_t)nB * HD + cg16;
        #pragma unroll
        for (int jj = 0; jj < 16; ++jj) whp[jj] = __float2bfloat16(acc1[jj]);
        p.sdot[ri][(size_t)nB * 4 + cg] = s1;
      }
    }
  }
}

// ---------------------------------------------------------------------------
// CSR build: histogram -> scan -> scatter(+alpha)
// ---------------------------------------------------------------------------
constexpr int SCAN_TPB   = 256;
constexpr int SCAN_ELEMS = 8;
constexpr int SCAN_CHUNK = SCAN_TPB * SCAN_ELEMS;  // 2048

__global__ __launch_bounds__(256) void zero_u32_kernel(unsigned* p, int n) {
  const int i = blockIdx.x * 256 + threadIdx.x;
  if (i < n) p[i] = 0u;
}

struct EdgeLists { const int* src[9]; const int* dst[9]; int E; int N; };

__global__ __launch_bounds__(256) void hist_kernel(EdgeLists el, unsigned* counts) {
  const int r = blockIdx.y;
  const int e = blockIdx.x * 256 + threadIdx.x;
  if (e < el.E) atomicAdd(counts + (size_t)r * el.N + el.dst[r][e], 1u);
}

__global__ __launch_bounds__(SCAN_TPB) void scan1_kernel(const unsigned* counts,
                                                         unsigned* partials,
                                                         int N, int nblk) {
  const int r = blockIdx.y;
  const int b = blockIdx.x;
  const unsigned* c = counts + (size_t)r * N;
  const int base = b * SCAN_CHUNK + threadIdx.x * SCAN_ELEMS;
  unsigned s = 0;
  #pragma unroll
  for (int i = 0; i < SCAN_ELEMS; ++i) {
    const int idx = base + i;
    if (idx < N) s += c[idx];
  }
  __shared__ unsigned red[SCAN_TPB];
  red[threadIdx.x] = s;
  __syncthreads();
  for (int off = SCAN_TPB / 2; off > 0; off >>= 1) {
    if (threadIdx.x < off) red[threadIdx.x] += red[threadIdx.x + off];
    __syncthreads();
  }
  if (threadIdx.x == 0) partials[(size_t)r * nblk + b] = red[0];
}

__global__ __launch_bounds__(64) void scan2_kernel(unsigned* partials, int nblk) {
  const int r = blockIdx.x;
  unsigned* p = partials + (size_t)r * nblk;
  if (threadIdx.x == 0) {
    unsigned run = 0;
    for (int i = 0; i < nblk; ++i) { const unsigned v = p[i]; p[i] = run; run += v; }
  }
}

__global__ __launch_bounds__(SCAN_TPB) void scan3_kernel(const unsigned* counts,
                                                         const unsigned* partials,
                                                         unsigned* offsets,
                                                         unsigned* cursor,
                                                         int N, int nblk, int E) {
  const int r = blockIdx.y;
  const int b = blockIdx.x;
  const unsigned* c = counts + (size_t)r * N;
  unsigned* off = offsets + (size_t)r * (N + 1);
  unsigned* cur = cursor + (size_t)r * N;
  const int base = b * SCAN_CHUNK + threadIdx.x * SCAN_ELEMS;
  unsigned loc[SCAN_ELEMS];
  unsigned s = 0;
  #pragma unroll
  for (int i = 0; i < SCAN_ELEMS; ++i) {
    const int idx = base + i;
    const unsigned v = (idx < N) ? c[idx] : 0u;
    loc[i] = v; s += v;
  }
  __shared__ unsigned tsum[SCAN_TPB];
  tsum[threadIdx.x] = s;
  __syncthreads();
  for (int d = 1; d < SCAN_TPB; d <<= 1) {
    const unsigned v = tsum[threadIdx.x];
    const unsigned a = (threadIdx.x >= d) ? tsum[threadIdx.x - d] : 0u;
    __syncthreads();
    tsum[threadIdx.x] = v + a;
    __syncthreads();
  }
  unsigned run = partials[(size_t)r * nblk + b] + tsum[threadIdx.x] - s;  // exclusive
  #pragma unroll
  for (int i = 0; i < SCAN_ELEMS; ++i) {
    const int idx = base + i;
    if (idx < N) { off[idx] = run; cur[idx] = run; run += loc[i]; }
  }
  if (b == 0 && threadIdx.x == 0) off[N] = (unsigned)E;
}

// scatter + alpha: needs sdot/ddot (proj must run first)
struct ScatterParams {
  unsigned* cursor;          // [9*N]
  unsigned* perm;            // [9*E] src ids in dst order
  __hip_bfloat16* alf;       // [9*E*4] per-edge alpha (bf16), CSR order
  const float* sdot[9];
  const float* ddot[9];
};

__global__ __launch_bounds__(256) void scatter_alpha_kernel(EdgeLists el, ScatterParams sp) {
  const int r = blockIdx.y;
  const int e = blockIdx.x * 256 + threadIdx.x;
  if (e >= el.E) return;
  const int s = el.src[r][e];
  const int d = el.dst[r][e];
  const unsigned pos = atomicAdd(sp.cursor + (size_t)r * el.N + d, 1u);
  sp.perm[(size_t)r * el.E + pos] = (unsigned)s;

  const float4 sd = *(const float4*)(sp.sdot[r] + (size_t)s * 4);
  const float4 dd = *(const float4*)(sp.ddot[r] + (size_t)d * 4);
  float e0 = sd.x + dd.x, e1 = sd.y + dd.y, e2 = sd.z + dd.z, e3 = sd.w + dd.w;
  e0 = (e0 >= 0.f) ? e0 : 0.2f * e0;
  e1 = (e1 >= 0.f) ? e1 : 0.2f * e1;
  e2 = (e2 >= 0.f) ? e2 : 0.2f * e2;
  e3 = (e3 >= 0.f) ? e3 : 0.2f * e3;
  const float m = fmaxf(fmaxf(e0, e1), fmaxf(e2, e3));
  const float x0 = __expf(e0 - m);
  const float x1 = __expf(e1 - m);
  const float x2 = __expf(e2 - m);
  const float x3 = __expf(e3 - m);
  const float inv = 1.f / (x0 + x1 + x2 + x3);
  const unsigned short b0 = f2bf_bits(x0 * inv);
  const unsigned short b1 = f2bf_bits(x1 * inv);
  const unsigned short b2 = f2bf_bits(x2 * inv);
  const unsigned short b3 = f2bf_bits(x3 * inv);
  uint2 packed;
  packed.x = ((unsigned)b1 << 16) | b0;
  packed.y = ((unsigned)b3 << 16) | b2;
  *(uint2*)(sp.alf + ((size_t)r * el.E + pos) * 4) = packed;
}

// ---------------------------------------------------------------------------
// Aggregation: one 64-lane wave per (dst node, type); 4 edge-slots x 16 lanes.
//   lane = slot*16 + l16; lane covers cols [4*l16, 4*l16+3] (within head l16>>2)
// ---------------------------------------------------------------------------
struct AggParams {
  const unsigned* offsets[9];        // [N+1]
  const unsigned* perm[9];           // [E]
  const __hip_bfloat16* alf[9];      // [E*4]
  const unsigned short* wh[9];       // [N*64] bf16 bits
  float* outp[3];
  int N, E;
};

typedef __attribute__((ext_vector_type(4))) unsigned short us4;

__global__ __launch_bounds__(256) void agg_kernel(AggParams p) {
  const int t    = blockIdx.y;
  const int w    = threadIdx.x >> 6;
  const int lane = threadIdx.x & 63;
  const int n    = blockIdx.x * 4 + w;
  if (n >= p.N) return;
  const int slot = lane >> 4;       // edge slot 0..3
  const int l16  = lane & 15;       // col group
  const int h    = l16 >> 2;        // head of cols 4*l16..4*l16+3

  float acc0 = 0.f, acc1 = 0.f, acc2 = 0.f, acc3 = 0.f;

  #pragma unroll
  for (int sj = 0; sj < 3; ++sj) {
    const int r = sj * 3 + t;
    const unsigned start = p.offsets[r][n];
    const unsigned end   = p.offsets[r][n + 1];
    const unsigned* pm = p.perm[r];
    const __hip_bfloat16* al = p.alf[r];
    const unsigned short* whr = p.wh[r];

    for (unsigned base = start; base < end; base += 4) {
      const unsigned pos  = base + slot;
      const unsigned posc = (pos < end) ? pos : (end - 1);
      const unsigned s = pm[posc];
      float a = bf2f(*(const unsigned short*)(al + posc * 4 + h));
      if (pos >= end) a = 0.f;
      const us4 wv = *(const us4*)(whr + (size_t)s * HD + l16 * 4);
      acc0 = fmaf(a, bf2f(wv.x), acc0);
      acc1 = fmaf(a, bf2f(wv.y), acc1);
      acc2 = fmaf(a, bf2f(wv.z), acc2);
      acc3 = fmaf(a, bf2f(wv.w), acc3);
    }
  }

  // reduce the 4 edge-slots (lanes differing in bits 4..5)
  acc0 += __shfl_xor(acc0, 16); acc1 += __shfl_xor(acc1, 16);
  acc2 += __shfl_xor(acc2, 16); acc3 += __shfl_xor(acc3, 16);
  acc0 += __shfl_xor(acc0, 32); acc1 += __shfl_xor(acc1, 32);
  acc2 += __shfl_xor(acc2, 32); acc3 += __shfl_xor(acc3, 32);

  if (slot == 0) {
    float4 v;
    v.x = fmaxf(acc0, 0.f); v.y = fmaxf(acc1, 0.f);
    v.z = fmaxf(acc2, 0.f); v.w = fmaxf(acc3, 0.f);
    *(float4*)(p.outp[t] + (size_t)n * HD + l16 * 4) = v;
  }
}

// ---------------------------------------------------------------------------
extern "C" void kernel_launch(void* const* d_in, const int* in_sizes, int n_in,
                              void* d_out, int out_size, void* d_ws, size_t ws_size,
                              hipStream_t stream) {
  const int N = in_sizes[0] / IN_F;     // 100000
  const int E = in_sizes[9 + 4];        // 400000

  ProjParams pp; AggParams ap; EdgeLists el; ScatterParams sp;
  pp.N = N; ap.N = N; ap.E = E; el.E = E; el.N = N;

  for (int t = 0; t < 3; ++t) {
    pp.feat[t]  = (const float*)d_in[t * 3 + 0];
    pp.Wp[t][0] = (const float*)d_in[t * 3 + 1];
    pp.bp[t][0] = (const float*)d_in[t * 3 + 2];
    for (int j = 0; j < 3; ++j) {
      const int base = 9 + (t * 3 + j) * 6;
      pp.Wp[t][1 + j] = (const float*)d_in[base + 0];
      pp.bp[t][1 + j] = (const float*)d_in[base + 1];
    }
  }

  // workspace carve-up
  char* ws = (char*)d_ws;
  const size_t whBytes  = (size_t)N * HD * sizeof(__hip_bfloat16); // 12.8 MB
  const size_t dotBytes = (size_t)N * 4 * sizeof(float);           // 1.6 MB
  char* whBase   = ws;                                  // 9 * 12.8 MB
  char* sdotBase = whBase + 9 * whBytes;                // 9 * 1.6 MB
  char* ddotBase = sdotBase + 9 * dotBytes;             // 9 * 1.6 MB
  unsigned* counts   = (unsigned*)(ddotBase + 9 * dotBytes);   // 9*N
  unsigned* cursor   = counts + (size_t)9 * N;                 // 9*N
  unsigned* offsets  = cursor + (size_t)9 * N;                 // 9*(N+1)
  unsigned* partials = offsets + (size_t)9 * (N + 1);
  const int nblk = (N + SCAN_CHUNK - 1) / SCAN_CHUNK;          // 49
  unsigned* perm = partials + (size_t)9 * ((nblk + 63) & ~63); // 9*E
  __hip_bfloat16* alf = (__hip_bfloat16*)(perm + (size_t)9 * E); // 9*E*4 bf16

  sp.cursor = cursor; sp.perm = perm; sp.alf = alf;

  for (int ri = 0; ri < 9; ++ri) {
    const int base = 9 + ri * 6;
    pp.asrc[ri] = (const float*)d_in[base + 2];
    pp.adst[ri] = (const float*)d_in[base + 3];
    pp.wh[ri]   = (__hip_bfloat16*)(whBase + (size_t)ri * whBytes);
    pp.sdot[ri] = (float*)(sdotBase + (size_t)ri * dotBytes);
    pp.ddot[ri] = (float*)(ddotBase + (size_t)ri * dotBytes);
    el.src[ri]  = (const int*)d_in[base + 4];
    el.dst[ri]  = (const int*)d_in[base + 5];
    sp.sdot[ri] = pp.sdot[ri];
    sp.ddot[ri] = pp.ddot[ri];
    ap.wh[ri]   = (const unsigned short*)pp.wh[ri];
    ap.alf[ri]  = alf + (size_t)ri * E * 4;
    ap.offsets[ri] = offsets + (size_t)ri * (N + 1);
    ap.perm[ri]    = perm + (size_t)ri * E;
  }
  for (int t = 0; t < 3; ++t) ap.outp[t] = (float*)d_out + (size_t)t * N * HD;

  // ---- CSR histogram + scan (independent of proj) ----
  const int nCounts = 9 * N;
  zero_u32_kernel<<<dim3((nCounts + 255) / 256), 256, 0, stream>>>(counts, nCounts);
  hist_kernel<<<dim3((E + 255) / 256, 9), 256, 0, stream>>>(el, counts);
  scan1_kernel<<<dim3(nblk, 9), SCAN_TPB, 0, stream>>>(counts, partials, N, nblk);
  scan2_kernel<<<dim3(9), 64, 0, stream>>>(partials, nblk);
  scan3_kernel<<<dim3(nblk, 9), SCAN_TPB, 0, stream>>>(counts, partials, offsets, cursor, N, nblk, E);

  // ---- projections (produce wh, sdot, ddot) ----
  proj_kernel<<<dim3((N + BN - 1) / BN, 3), 256, 0, stream>>>(pp);

  // ---- scatter src ids + per-edge alpha into CSR order ----
  scatter_alpha_kernel<<<dim3((E + 255) / 256, 9), 256, 0, stream>>>(el, sp);

  // ---- dst-centric aggregation (exactly one write per output elem) ----
  agg_kernel<<<dim3((N + 3) / 4, 3), 256, 0, stream>>>(ap);
}